// Round 3
// baseline (1217.517 us; speedup 1.0000x reference)
//
#include <hip/hip_runtime.h>

#define BATCH 16
#define SEQ 4096
#define DIM 1024
#define NHEADS 16
#define HDIM 64
#define EPS 1e-5f

typedef __bf16 bf16x8 __attribute__((ext_vector_type(8)));
typedef __bf16 bf16x4 __attribute__((ext_vector_type(4)));
typedef float f32x4 __attribute__((ext_vector_type(4)));

// ---------------- kernel 1: layernorm of q (16 heads x 64) ----------------
__global__ __launch_bounds__(1024) void qnorm_kernel(
    const float* __restrict__ q, const float* __restrict__ wn,
    const float* __restrict__ bn, float* __restrict__ qn)
{
  const int tid = threadIdx.x;     // 1024 threads = 16 waves, one head per wave
  const int lane = tid & 63;
  float v = q[tid];
  float s = v;
  #pragma unroll
  for (int o = 1; o < 64; o <<= 1) s += __shfl_xor(s, o, 64);
  const float mu = s * (1.0f / 64.0f);
  const float d = v - mu;
  float sq = d * d;
  #pragma unroll
  for (int o = 1; o < 64; o <<= 1) sq += __shfl_xor(sq, o, 64);
  const float rstd = rsqrtf(sq * (1.0f / 64.0f) + EPS);
  qn[tid] = d * rstd * wn[lane] + bn[lane];
}

// ---------------- kernel 2: K = x @ wk^T + bk, fused LN + q-dot -> scores ----
// grid 4096: mt = bid>>3 (512 m-tiles of 128 rows), nt = bid&7 (128 cols = 2 heads)
// 256 threads = 4 waves (2x2), each wave computes a 64x64 tile = one head.
__global__ __launch_bounds__(256, 2) void score_gemm_kernel(
    const float* __restrict__ x, const float* __restrict__ wk,
    const float* __restrict__ bk, const float* __restrict__ qn,
    const float* __restrict__ wn, const float* __restrict__ bn,
    float* __restrict__ scores)
{
  __shared__ __bf16 As[128 * 64];   // 16 KB, XOR-swizzled 16B chunks
  __shared__ __bf16 Bs[128 * 64];   // 16 KB

  const int bid = blockIdx.x;
  const int mt = bid >> 3;
  const int nt = bid & 7;
  const int m0 = mt << 7;
  const int n0 = nt << 7;
  const int tid = threadIdx.x;
  const int lane = tid & 63;
  const int wave = tid >> 6;
  const int wr = wave >> 1;
  const int wc = wave & 1;

  f32x4 acc[4][4] = {};

  for (int ks = 0; ks < DIM; ks += 64) {
    __syncthreads();
    // stage A: 128 rows x 64 k, f32 -> bf16, swizzle pc = c ^ (row&7)
    #pragma unroll
    for (int i = 0; i < 8; ++i) {
      const int id = i * 256 + tid;      // 0..2047
      const int row = id >> 4;
      const int cc = id & 15;            // 4-float granule within 64-wide slice
      const float4 v = *(const float4*)(x + (size_t)(m0 + row) * DIM + ks + cc * 4);
      bf16x4 bv = { (__bf16)v.x, (__bf16)v.y, (__bf16)v.z, (__bf16)v.w };
      const int off = row * 128 + (((cc >> 1) ^ (row & 7)) << 4) + ((cc & 1) << 3);
      *(bf16x4*)((char*)As + off) = bv;
    }
    // stage B: wk rows n0..n0+127
    #pragma unroll
    for (int i = 0; i < 8; ++i) {
      const int id = i * 256 + tid;
      const int row = id >> 4;
      const int cc = id & 15;
      const float4 v = *(const float4*)(wk + (size_t)(n0 + row) * DIM + ks + cc * 4);
      bf16x4 bv = { (__bf16)v.x, (__bf16)v.y, (__bf16)v.z, (__bf16)v.w };
      const int off = row * 128 + (((cc >> 1) ^ (row & 7)) << 4) + ((cc & 1) << 3);
      *(bf16x4*)((char*)Bs + off) = bv;
    }
    __syncthreads();
    #pragma unroll
    for (int kk = 0; kk < 2; ++kk) {
      bf16x8 af[4], bfr[4];
      const int kc = (kk << 2) + (lane >> 4);  // logical 16B chunk 0..7
      #pragma unroll
      for (int mi = 0; mi < 4; ++mi) {
        const int row = (wr << 6) + (mi << 4) + (lane & 15);
        af[mi] = *(const bf16x8*)((const char*)As + row * 128 + ((kc ^ (row & 7)) << 4));
      }
      #pragma unroll
      for (int ni = 0; ni < 4; ++ni) {
        const int row = (wc << 6) + (ni << 4) + (lane & 15);
        bfr[ni] = *(const bf16x8*)((const char*)Bs + row * 128 + ((kc ^ (row & 7)) << 4));
      }
      #pragma unroll
      for (int mi = 0; mi < 4; ++mi)
        #pragma unroll
        for (int ni = 0; ni < 4; ++ni)
          acc[mi][ni] = __builtin_amdgcn_mfma_f32_16x16x32_bf16(
              af[mi], bfr[ni], acc[mi][ni], 0, 0, 0);
    }
  }

  // epilogue: per-row (over this wave's head, 64 cols) LN + dot(q_norm)
  // C layout: col = lane&15 (within 16-tile ni), row = (lane>>4)*4 + j (within mi)
  const int h = (nt << 1) + wc;
  const int g = lane >> 4;
  const int c = lane & 15;
  float wnv[4], bnv[4], qv[4], bkv[4];
  #pragma unroll
  for (int ni = 0; ni < 4; ++ni) {
    const int d = (ni << 4) + c;
    wnv[ni] = wn[d];
    bnv[ni] = bn[d];
    qv[ni]  = qn[h * HDIM + d];
    bkv[ni] = bk[h * HDIM + d];
  }
  #pragma unroll
  for (int mi = 0; mi < 4; ++mi) {
    float v[4][4];
    float s[4]  = {0.f, 0.f, 0.f, 0.f};
    float sq[4] = {0.f, 0.f, 0.f, 0.f};
    #pragma unroll
    for (int ni = 0; ni < 4; ++ni)
      #pragma unroll
      for (int j = 0; j < 4; ++j) {
        const float t = acc[mi][ni][j] + bkv[ni];
        v[ni][j] = t;
        s[j] += t;
        sq[j] += t * t;
      }
    #pragma unroll
    for (int o = 1; o < 16; o <<= 1)
      #pragma unroll
      for (int j = 0; j < 4; ++j) {
        s[j]  += __shfl_xor(s[j], o, 64);
        sq[j] += __shfl_xor(sq[j], o, 64);
      }
    float sc[4];
    #pragma unroll
    for (int j = 0; j < 4; ++j) {
      const float mu = s[j] * (1.0f / 64.0f);
      const float var = sq[j] * (1.0f / 64.0f) - mu * mu;
      const float rstd = rsqrtf(var + EPS);
      float pp = 0.f;
      #pragma unroll
      for (int ni = 0; ni < 4; ++ni)
        pp += ((v[ni][j] - mu) * rstd * wnv[ni] + bnv[ni]) * qv[ni];
      sc[j] = pp;
    }
    #pragma unroll
    for (int o = 1; o < 16; o <<= 1)
      #pragma unroll
      for (int j = 0; j < 4; ++j) sc[j] += __shfl_xor(sc[j], o, 64);
    if (c == 0) {
      #pragma unroll
      for (int j = 0; j < 4; ++j) {
        const int rl = (wr << 6) + (mi << 4) + (g << 2) + j;
        const int m = m0 + rl;
        const int b = m >> 12;
        const int l = m & 4095;
        scores[(((size_t)b * NHEADS + h) << 12) + l] = sc[j] * 0.125f;
      }
    }
  }
}

// ---------------- kernel 3: softmax over l per (b,h), in-place --------------
__global__ __launch_bounds__(256) void softmax_kernel(float* __restrict__ sc)
{
  __shared__ float red[8];
  const int tid = threadIdx.x;
  const int lane = tid & 63;
  const int w = tid >> 6;
  float* s = sc + (size_t)blockIdx.x * SEQ;
  float4 v[4];
  float mx = -1e30f;
  #pragma unroll
  for (int i = 0; i < 4; ++i) {
    v[i] = *(const float4*)(s + tid * 16 + i * 4);
    mx = fmaxf(mx, fmaxf(fmaxf(v[i].x, v[i].y), fmaxf(v[i].z, v[i].w)));
  }
  #pragma unroll
  for (int o = 1; o < 64; o <<= 1) mx = fmaxf(mx, __shfl_xor(mx, o, 64));
  if (lane == 0) red[w] = mx;
  __syncthreads();
  mx = fmaxf(fmaxf(red[0], red[1]), fmaxf(red[2], red[3]));
  float sum = 0.f;
  #pragma unroll
  for (int i = 0; i < 4; ++i) {
    v[i].x = expf(v[i].x - mx); v[i].y = expf(v[i].y - mx);
    v[i].z = expf(v[i].z - mx); v[i].w = expf(v[i].w - mx);
    sum += v[i].x + v[i].y + v[i].z + v[i].w;
  }
  #pragma unroll
  for (int o = 1; o < 64; o <<= 1) sum += __shfl_xor(sum, o, 64);
  if (lane == 0) red[4 + w] = sum;
  __syncthreads();
  sum = red[4] + red[5] + red[6] + red[7];
  const float inv = 1.0f / sum;
  #pragma unroll
  for (int i = 0; i < 4; ++i) {
    v[i].x *= inv; v[i].y *= inv; v[i].z *= inv; v[i].w *= inv;
    *(float4*)(s + tid * 16 + i * 4) = v[i];
  }
}

// ---------------- kernel 4: p[b,h,:] = sum_l attn[b,h,l] * x[b,l,:] ---------
// grid 1024 = b(16) x dc(8: 128-dim chunk) x lc(8: 512-l chunk); atomics into p
__global__ __launch_bounds__(256) void pool_kernel(
    const float* __restrict__ x, const float* __restrict__ attn,
    float* __restrict__ p)
{
  __shared__ float at[128][16];   // [l][h]
  const int bid = blockIdx.x;
  const int b = bid >> 6;
  const int dc = (bid >> 3) & 7;
  const int lc = bid & 7;
  const int tid = threadIdx.x;
  const int d = tid & 127;
  const int lh = tid >> 7;

  float acc[16];
  #pragma unroll
  for (int i = 0; i < 16; ++i) acc[i] = 0.f;

  const float* xp = x + ((size_t)b * SEQ + lc * 512) * DIM + dc * 128 + d;
  const float* ap = attn + (size_t)b * NHEADS * SEQ + lc * 512;

  for (int ch = 0; ch < 4; ++ch) {
    __syncthreads();
    for (int i = tid; i < 128 * 16; i += 256) {
      const int hh = i & 15;
      const int ll = i >> 4;
      at[ll][hh] = ap[(size_t)hh * SEQ + ch * 128 + ll];
    }
    __syncthreads();
    for (int l = lh; l < 128; l += 2) {
      const float xv = xp[(size_t)(ch * 128 + l) * DIM];
      const f32x4* ar = (const f32x4*)&at[l][0];
      const f32x4 a0 = ar[0], a1 = ar[1], a2 = ar[2], a3 = ar[3];
      acc[0]  += a0[0] * xv; acc[1]  += a0[1] * xv; acc[2]  += a0[2] * xv; acc[3]  += a0[3] * xv;
      acc[4]  += a1[0] * xv; acc[5]  += a1[1] * xv; acc[6]  += a1[2] * xv; acc[7]  += a1[3] * xv;
      acc[8]  += a2[0] * xv; acc[9]  += a2[1] * xv; acc[10] += a2[2] * xv; acc[11] += a2[3] * xv;
      acc[12] += a3[0] * xv; acc[13] += a3[1] * xv; acc[14] += a3[2] * xv; acc[15] += a3[3] * xv;
    }
  }
  #pragma unroll
  for (int hh = 0; hh < 16; ++hh)
    atomicAdd(&p[((size_t)b * NHEADS + hh) * DIM + dc * 128 + d], acc[hh]);
}

// ---------------- kernel 5: o[b, h*64+d'] = p[b,h,:] . wv[h*64+d',:] + bv ----
// grid 64: blk = h*4+dq -> w rows r0=blk*16; threads: d'=tid&15, b=tid>>4
__global__ __launch_bounds__(256) void ov_kernel(
    const float* __restrict__ p, const float* __restrict__ wv,
    const float* __restrict__ bv, float* __restrict__ o)
{
  __shared__ float wsw[16][1024];   // XOR-swizzled 16B chunks
  const int blk = blockIdx.x;
  const int h = blk >> 2;
  const int r0 = blk << 4;
  const int tid = threadIdx.x;
  for (int i = tid; i < 4096; i += 256) {
    const int r = i >> 8;
    const int cq = i & 255;
    *(float4*)&wsw[r][(cq ^ (r & 7)) << 2] =
        *(const float4*)(wv + (size_t)(r0 + r) * DIM + (cq << 2));
  }
  __syncthreads();
  const int d = tid & 15;
  const int b = tid >> 4;
  const float* pp = p + ((size_t)b * NHEADS + h) * DIM;
  float acc = 0.f;
  for (int k = 0; k < DIM; k += 4) {
    const float4 w4 = *(const float4*)&wsw[d][((k >> 2) ^ (d & 7)) << 2];
    const float4 p4 = *(const float4*)(pp + k);
    acc += w4.x * p4.x + w4.y * p4.y + w4.z * p4.z + w4.w * p4.w;
  }
  o[(size_t)b * DIM + r0 + d] = acc + bv[r0 + d];
}

// ---------------- kernel 6: out[b,:] = o[b,:] @ wout^T + bout ---------------
__global__ __launch_bounds__(256) void out_kernel(
    const float* __restrict__ o, const float* __restrict__ wout,
    const float* __restrict__ bout, float* __restrict__ out)
{
  __shared__ float wsw[16][1024];
  const int blk = blockIdx.x;
  const int r0 = blk << 4;
  const int tid = threadIdx.x;
  for (int i = tid; i < 4096; i += 256) {
    const int r = i >> 8;
    const int cq = i & 255;
    *(float4*)&wsw[r][(cq ^ (r & 7)) << 2] =
        *(const float4*)(wout + (size_t)(r0 + r) * DIM + (cq << 2));
  }
  __syncthreads();
  const int d = tid & 15;
  const int b = tid >> 4;
  const float* op = o + (size_t)b * DIM;
  float acc = 0.f;
  for (int k = 0; k < DIM; k += 4) {
    const float4 w4 = *(const float4*)&wsw[d][((k >> 2) ^ (d & 7)) << 2];
    const float4 o4 = *(const float4*)(op + k);
    acc += w4.x * o4.x + w4.y * o4.y + w4.z * o4.z + w4.w * o4.w;
  }
  out[(size_t)b * DIM + r0 + d] = acc + bout[r0 + d];
}

extern "C" void kernel_launch(void* const* d_in, const int* in_sizes, int n_in,
                              void* d_out, int out_size, void* d_ws, size_t ws_size,
                              hipStream_t stream) {
  (void)in_sizes; (void)n_in; (void)out_size; (void)ws_size;
  const float* x      = (const float*)d_in[0];
  const float* query  = (const float*)d_in[1];
  const float* w_k    = (const float*)d_in[2];
  const float* b_k    = (const float*)d_in[3];
  const float* w_v    = (const float*)d_in[4];
  const float* b_v    = (const float*)d_in[5];
  const float* w_norm = (const float*)d_in[6];
  const float* b_norm = (const float*)d_in[7];
  const float* w_out  = (const float*)d_in[8];
  const float* b_out  = (const float*)d_in[9];
  float* out = (float*)d_out;

  char* ws = (char*)d_ws;
  float* qn     = (float*)ws;                                   // 4 KB
  float* scores = (float*)(ws + 8192);                          // 4 MB (attn in-place)
  float* p      = (float*)(ws + 8192 + (size_t)BATCH * NHEADS * SEQ * 4);  // 1 MB
  float* o      = (float*)((char*)p + (size_t)BATCH * NHEADS * DIM * 4);   // 64 KB

  hipMemsetAsync(p, 0, (size_t)BATCH * NHEADS * DIM * 4, stream);
  qnorm_kernel<<<1, 1024, 0, stream>>>(query, w_norm, b_norm, qn);
  score_gemm_kernel<<<4096, 256, 0, stream>>>(x, w_k, b_k, qn, w_norm, b_norm, scores);
  softmax_kernel<<<BATCH * NHEADS, 256, 0, stream>>>(scores);
  pool_kernel<<<1024, 256, 0, stream>>>(x, scores, p);
  ov_kernel<<<64, 256, 0, stream>>>(p, w_v, b_v, o);
  out_kernel<<<64, 256, 0, stream>>>(o, w_out, b_out, out);
}